// Round 12
// baseline (2197.777 us; speedup 1.0000x reference)
//
#include <hip/hip_runtime.h>
#include <hip/hip_bf16.h>

// GCN 2-layer forward, fp32 I/O. Phased LDS-accumulator aggregation:
// edges grouped into 128-dst-node segments, sorted by src-phase (src>>11);
// one block per segment accumulates gathered rows into LDS (fp32), so the
// concurrent cohort sweeps the h' table phase-by-phase -> gathers hit the
// per-XCD L2 instead of random L3 (the r11 bottleneck: 3.6 TB/s L3 random).
// dinv folded into stored rows (h1' = dinv*(x@W1) etc, pulls are gather+add).
// Pipeline:
//  1) k_prep: W1,W2 -> bf16 transposed; bcur[b] = b*CAP
//  2) k_bucket: partition packed {src,q=dst&511} by dst>>9 into ebuf
//  3) k_bcsr:  per-bucket LDS stage -> node hist (dinv) -> key=(sub,phase)
//              counting sort -> csr4 = (src<<7)|dloc ; segbeg/segcnt per
//              128-node segment
//  4) h1' = dinv*(x @ W1) -> bf16                  (k_gemm1, MFMA)
//  5) aggb = dinv*(self + LDS-acc gather sum)      (k_pullacc128)
//  6) h2' = dinv*(relu(aggb+b1) @ W2) -> bf16      (k_gemm2, MFMA)
//  7) out = dinv*(self + LDS-acc sum) + b2         (k_pullacc64)

typedef short short8v __attribute__((ext_vector_type(8)));   // 8 bf16 (4 VGPRs)
typedef float f32x4   __attribute__((ext_vector_type(4)));   // MFMA acc

#define BSHIFT 9           // build bucket = dst >> 9 (512 nodes)
#define BSIZE  512
#define CAPSH  14          // per-bucket capacity 16384 (mean 8163, >40 sigma)
#define CAP    (1 << CAPSH)
#define PSH    11          // src phase = src >> 11 (2048 nodes = 512 KB h1')

// RNE fp32 -> bf16 (finite inputs)
__device__ __forceinline__ short f2bf(float f) {
    unsigned u = __float_as_uint(f);
    return (short)((u + 0x7fffu + ((u >> 16) & 1u)) >> 16);
}
__device__ __forceinline__ unsigned pack2bf(float a, float b) {
    return (unsigned)(unsigned short)f2bf(a) | ((unsigned)(unsigned short)f2bf(b) << 16);
}
__device__ __forceinline__ float bflo(unsigned u) { return __uint_as_float(u << 16); }
__device__ __forceinline__ float bfhi(unsigned u) { return __uint_as_float(u & 0xffff0000u); }

// ---- W prep + bucket-cursor init (one launch) ----
__global__ void k_prep(const float* __restrict__ W1, const float* __restrict__ W2,
                       short* __restrict__ w1t, short* __restrict__ w2t,
                       int* __restrict__ bcur, int nbuck) {
    int b = blockIdx.x;
    int t = threadIdx.x;
    if (b == gridDim.x - 1) {                 // last block: init bucket cursors
        if (t < nbuck) bcur[t] = t << CAPSH;
        return;
    }
    int i = b * 256 + t;                      // 96 blocks cover 24576 elems
    if (i < 128 * 128) {
        int n = i >> 7, k = i & 127;
        w1t[i] = f2bf(W1[k * 128 + n]);
    } else {
        int j = i - 128 * 128;
        int n = j >> 7, k = j & 127;
        w2t[j] = f2bf(W2[k * 64 + n]);
    }
}

// ---- partition edges into packed ebuf: entry = (src<<9) | (dst&511) ----
__global__ __launch_bounds__(256) void k_bucket(const int* __restrict__ src,
                                                const int* __restrict__ dst,
                                                int* __restrict__ bcur,
                                                unsigned* __restrict__ ebuf,
                                                int E, int nbuck) {
    __shared__ int sdst[4096];
    __shared__ int ssrc[4096];
    __shared__ int hist[256];
    __shared__ int base[256];
    int t = threadIdx.x;
    int e0 = blockIdx.x * 4096;
    for (int i = t; i < nbuck; i += 256) hist[i] = 0;
    for (int i = 0; i < 16; ++i) {                  // single global read
        int k = i * 256 + t;
        int e = e0 + k;
        sdst[k] = (e < E) ? dst[e] : -1;
        ssrc[k] = (e < E) ? src[e] : 0;
    }
    __syncthreads();
    for (int i = 0; i < 16; ++i) {                  // pass 1: LDS histogram
        int d = sdst[i * 256 + t];
        if (d >= 0) atomicAdd(&hist[d >> BSHIFT], 1);
    }
    __syncthreads();
    for (int b = t; b < nbuck; b += 256) {          // pass 2: reserve chunks
        int c = hist[b];
        base[b] = c ? atomicAdd(&bcur[b], c) : 0;
        hist[b] = 0;
    }
    __syncthreads();
    for (int i = 0; i < 16; ++i) {                  // pass 3: grouped writes
        int k = i * 256 + t;
        int d = sdst[k];
        if (d >= 0) {
            int bk = d >> BSHIFT;
            int off = atomicAdd(&hist[bk], 1);
            ebuf[base[bk] + off] = ((unsigned)ssrc[k] << BSHIFT) | (unsigned)(d & (BSIZE - 1));
        }
    }
}

// ---- per-bucket: node hist -> dinv; counting sort by key=(sub<<6)|phase
//      -> csr4 = (src<<7)|dloc, phase-sorted within 128-node segments ----
__global__ __launch_bounds__(BSIZE) void k_bcsr(const unsigned* __restrict__ ebuf,
                                                const int* __restrict__ bcur,
                                                float* __restrict__ dinv,
                                                unsigned* __restrict__ csr4,
                                                int* __restrict__ segbeg,
                                                int* __restrict__ segcnt, int n) {
    __shared__ unsigned edges[CAP];    // 64 KB
    __shared__ int hist[BSIZE];        // per-node degree
    __shared__ int keyc[256];          // (sub<<6)|phase counters -> cursors
    __shared__ int s[256];
    int b = blockIdx.x;
    int t = threadIdx.x;
    hist[t] = 0;
    if (t < 256) keyc[t] = 0;
    __syncthreads();
    int base = b << CAPSH;
    int cnt  = bcur[b] - base;
    int lo = b << BSHIFT;
    for (int k = t; k < cnt; k += BSIZE) {          // stage + hists
        unsigned e = ebuf[base + k];
        edges[k] = e;
        unsigned q = e & (BSIZE - 1);
        atomicAdd(&hist[q], 1);
        unsigned key = ((q >> 7) << 6) | ((e >> BSHIFT) >> PSH);
        atomicAdd(&keyc[key], 1);
    }
    __syncthreads();
    int node = lo + t;
    if (node < n) dinv[node] = rsqrtf((float)(hist[t] + 1));
    int v = 0;
    if (t < 256) { v = keyc[t]; s[t] = v; }
    __syncthreads();
    for (int off = 1; off < 256; off <<= 1) {       // inclusive scan (256 keys)
        int add = (t < 256 && t >= off) ? s[t - off] : 0;
        __syncthreads();
        if (t < 256) s[t] += add;
        __syncthreads();
    }
    if (t < 256) keyc[t] = base + s[t] - v;         // exclusive cursor
    __syncthreads();
    if (t < 4) {                                    // segment bounds
        int begp = keyc[t * 64];
        int endp = (t == 3) ? base + cnt : keyc[(t + 1) * 64];
        segbeg[b * 4 + t] = begp;
        segcnt[b * 4 + t] = endp - begp;
    }
    __syncthreads();
    for (int k = t; k < cnt; k += BSIZE) {          // sorted scatter
        unsigned e = edges[k];
        unsigned q = e & (BSIZE - 1);
        unsigned key = ((q >> 7) << 6) | ((e >> BSHIFT) >> PSH);
        int pos = atomicAdd(&keyc[key], 1);
        csr4[pos] = ((e >> BSHIFT) << 7) | (q & 127);
    }
}

// ---- MFMA GEMM1: h1'[64rows,128] = dinv*(bf16(x) @ bf16(W1)) ----
#define LDP 136
__global__ __launch_bounds__(256) void k_gemm1(const float* __restrict__ x,
                                               const short* __restrict__ w1t,
                                               const float* __restrict__ dinv,
                                               short* __restrict__ h, int nrows) {
    __shared__ short xs[64 * LDP];
    __shared__ short wt[128 * LDP];
    int t = threadIdx.x;
    int row0 = blockIdx.x * 64;
    for (int i = 0; i < 16; ++i) {
        int idx = t + i * 256;
        int r = idx >> 5, c4 = idx & 31;
        float4 v = make_float4(0.f, 0.f, 0.f, 0.f);
        if (row0 + r < nrows) v = ((const float4*)x)[(size_t)(row0 + r) * 32 + c4];
        short4 o = make_short4(f2bf(v.x), f2bf(v.y), f2bf(v.z), f2bf(v.w));
        *(short4*)&xs[r * LDP + c4 * 4] = o;
    }
    for (int i = 0; i < 16; ++i) {
        int idx = t + i * 256;
        int n = idx >> 5, c4 = idx & 31;
        *(short4*)&wt[n * LDP + c4 * 4] = ((const short4*)w1t)[idx];
    }
    __syncthreads();
    int wave = t >> 6, lane = t & 63;
    int quad = lane >> 4, c = lane & 15;
    int m0 = wave * 16;
    f32x4 acc[8] = {};
    #pragma unroll
    for (int kc = 0; kc < 4; ++kc) {
        short8v a = *(const short8v*)&xs[(m0 + c) * LDP + kc * 32 + quad * 8];
        #pragma unroll
        for (int nt = 0; nt < 8; ++nt) {
            short8v b = *(const short8v*)&wt[(nt * 16 + c) * LDP + kc * 32 + quad * 8];
            acc[nt] = __builtin_amdgcn_mfma_f32_16x16x32_bf16(a, b, acc[nt], 0, 0, 0);
        }
    }
    #pragma unroll
    for (int r = 0; r < 4; ++r) {
        int row = row0 + m0 + quad * 4 + r;
        if (row < nrows) {
            float dr = dinv[row];                   // fold norm into stored row
            #pragma unroll
            for (int nt = 0; nt < 8; ++nt)
                h[(size_t)row * 128 + nt * 16 + c] = f2bf(acc[nt][r] * dr);
        }
    }
}

// ---- MFMA GEMM2: h2'[64rows,64] = dinv*(bf16(relu(aggb+b1)) @ bf16(W2)) ----
__global__ __launch_bounds__(256) void k_gemm2(const unsigned* __restrict__ aggb, // bf16x2
                                               const float* __restrict__ b1,
                                               const short* __restrict__ w2t,
                                               const float* __restrict__ dinv,
                                               short* __restrict__ h2, int nrows) {
    __shared__ short xs[64 * LDP];
    __shared__ short wt[64 * LDP];
    int t = threadIdx.x;
    int row0 = blockIdx.x * 64;
    for (int i = 0; i < 16; ++i) {                    // 64 rows x 64 bf16-pairs
        int idx = t + i * 256;
        int r = idx >> 6, cp = idx & 63;
        unsigned o = 0;
        if (row0 + r < nrows) {
            unsigned u = aggb[(size_t)(row0 + r) * 64 + cp];
            float2 bb = ((const float2*)b1)[cp];
            float vx = fmaxf(bflo(u) + bb.x, 0.f);
            float vy = fmaxf(bfhi(u) + bb.y, 0.f);
            o = pack2bf(vx, vy);
        }
        *(unsigned*)&xs[r * LDP + cp * 2] = o;
    }
    for (int i = 0; i < 8; ++i) {
        int idx = t + i * 256;
        int n = idx >> 5, c4 = idx & 31;
        *(short4*)&wt[n * LDP + c4 * 4] = ((const short4*)w2t)[idx];
    }
    __syncthreads();
    int wave = t >> 6, lane = t & 63;
    int quad = lane >> 4, c = lane & 15;
    int m0 = wave * 16;
    f32x4 acc[4] = {};
    #pragma unroll
    for (int kc = 0; kc < 4; ++kc) {
        short8v av = *(const short8v*)&xs[(m0 + c) * LDP + kc * 32 + quad * 8];
        #pragma unroll
        for (int nt = 0; nt < 4; ++nt) {
            short8v b = *(const short8v*)&wt[(nt * 16 + c) * LDP + kc * 32 + quad * 8];
            acc[nt] = __builtin_amdgcn_mfma_f32_16x16x32_bf16(av, b, acc[nt], 0, 0, 0);
        }
    }
    #pragma unroll
    for (int r = 0; r < 4; ++r) {
        int row = row0 + m0 + quad * 4 + r;
        if (row < nrows) {
            float dr = dinv[row];
            #pragma unroll
            for (int nt = 0; nt < 4; ++nt)
                h2[(size_t)row * 64 + nt * 16 + c] = f2bf(acc[nt][r] * dr);
        }
    }
}

// ---- phased LDS-accumulator pull, 128 feats: one block per 128-node
// segment; acc layout [dloc][perm]: lane l holds uint (feats 2l,2l+1) ->
// acc[dloc*128 + l] (lo), acc[dloc*128 + 64 + l] (hi) — lane-linear banks.
__global__ __launch_bounds__(256) void k_pullacc128(const unsigned short* __restrict__ h,
                                                    const unsigned* __restrict__ csr4,
                                                    const int* __restrict__ segbeg,
                                                    const int* __restrict__ segcnt,
                                                    const float* __restrict__ dinv,
                                                    unsigned* __restrict__ aggb, int n) {
    __shared__ float acc[128 * 128];   // 64 KB
    int t = threadIdx.x;
    int p = blockIdx.x;
    int node0 = p << 7;
    const unsigned* hu = (const unsigned*)h;
    for (int idx = t; idx < 128 * 64; idx += 256) {   // self-term init
        int d = idx >> 6, l = idx & 63;
        int node = node0 + d;
        unsigned g = (node < n) ? hu[(size_t)node * 64 + l] : 0u;
        acc[d * 128 + l]      = bflo(g);
        acc[d * 128 + 64 + l] = bfhi(g);
    }
    __syncthreads();
    int beg = segbeg[p], cnt = segcnt[p];
    int wave = t >> 6, lane = t & 63;
    int k32 = cnt & ~31;
    for (int k0 = wave * 8; k0 < k32; k0 += 32) {     // 8 gathers in flight
        int e[8];
        unsigned g[8];
        #pragma unroll
        for (int j = 0; j < 8; ++j)
            e[j] = __builtin_amdgcn_readfirstlane((int)csr4[beg + k0 + j]);
        #pragma unroll
        for (int j = 0; j < 8; ++j)
            g[j] = hu[(size_t)((unsigned)e[j] >> 7) * 64 + lane];
        #pragma unroll
        for (int j = 0; j < 8; ++j) {
            int d = e[j] & 127;
            unsafeAtomicAdd(&acc[d * 128 + lane], bflo(g[j]));
            unsafeAtomicAdd(&acc[d * 128 + 64 + lane], bfhi(g[j]));
        }
    }
    for (int k = k32 + wave; k < cnt; k += 4) {       // tail
        int e = __builtin_amdgcn_readfirstlane((int)csr4[beg + k]);
        unsigned g = hu[(size_t)((unsigned)e >> 7) * 64 + lane];
        int d = e & 127;
        unsafeAtomicAdd(&acc[d * 128 + lane], bflo(g));
        unsafeAtomicAdd(&acc[d * 128 + 64 + lane], bfhi(g));
    }
    __syncthreads();
    for (int idx = t; idx < 128 * 64; idx += 256) {   // writeout * dinv
        int d = idx >> 6, l = idx & 63;
        int node = node0 + d;
        if (node < n) {
            float di = dinv[node];
            aggb[(size_t)node * 64 + l] =
                pack2bf(acc[d * 128 + l] * di, acc[d * 128 + 64 + l] * di);
        }
    }
}

// ---- phased LDS-accumulator pull, 64 feats, fused +b2 -> out (fp32).
// Half-wave per edge (row = 32 uints); acc [dloc][perm] 32 KB.
__global__ __launch_bounds__(256) void k_pullacc64(const unsigned short* __restrict__ h,
                                                   const unsigned* __restrict__ csr4,
                                                   const int* __restrict__ segbeg,
                                                   const int* __restrict__ segcnt,
                                                   const float* __restrict__ dinv,
                                                   const float* __restrict__ b2,
                                                   float* __restrict__ out, int n) {
    __shared__ float acc[128 * 64];    // 32 KB
    int t = threadIdx.x;
    int p = blockIdx.x;
    int node0 = p << 7;
    const unsigned* hu = (const unsigned*)h;
    for (int idx = t; idx < 128 * 32; idx += 256) {   // self-term init
        int d = idx >> 5, l = idx & 31;
        int node = node0 + d;
        unsigned g = (node < n) ? hu[(size_t)node * 32 + l] : 0u;
        acc[d * 64 + l]      = bflo(g);
        acc[d * 64 + 32 + l] = bfhi(g);
    }
    __syncthreads();
    int beg = segbeg[p], cnt = segcnt[p];
    int wave = t >> 6, lane = t & 63;
    int half = lane >> 5, l = lane & 31;
    int k32 = cnt & ~31;
    for (int k0 = wave * 8; k0 < k32; k0 += 32) {     // 8 edges per wave-iter
        unsigned e[4], g[4];
        #pragma unroll
        for (int j = 0; j < 4; ++j) e[j] = csr4[beg + k0 + j * 2 + half];
        #pragma unroll
        for (int j = 0; j < 4; ++j) g[j] = hu[(size_t)(e[j] >> 7) * 32 + l];
        #pragma unroll
        for (int j = 0; j < 4; ++j) {
            int d = e[j] & 127;
            unsafeAtomicAdd(&acc[d * 64 + l], bflo(g[j]));
            unsafeAtomicAdd(&acc[d * 64 + 32 + l], bfhi(g[j]));
        }
    }
    for (int k = k32 + wave * 2 + half; k < cnt; k += 8) {  // tail
        unsigned e = csr4[beg + k];
        unsigned g = hu[(size_t)(e >> 7) * 32 + l];
        int d = e & 127;
        unsafeAtomicAdd(&acc[d * 64 + l], bflo(g));
        unsafeAtomicAdd(&acc[d * 64 + 32 + l], bfhi(g));
    }
    __syncthreads();
    for (int idx = t; idx < 128 * 64; idx += 256) {   // writeout * dinv + b2
        int d = idx >> 6, f = idx & 63;
        int node = node0 + d;
        if (node < n) {
            float val = acc[d * 64 + ((f & 1) << 5) + (f >> 1)];
            out[(size_t)node * 64 + f] = val * dinv[node] + b2[f];
        }
    }
}

extern "C" void kernel_launch(void* const* d_in, const int* in_sizes, int n_in,
                              void* d_out, int out_size, void* d_ws, size_t ws_size,
                              hipStream_t stream) {
    const float* x  = (const float*)d_in[0];
    const int*   ei = (const int*)d_in[1];
    const float* W1 = (const float*)d_in[2];
    const float* b1 = (const float*)d_in[3];
    const float* W2 = (const float*)d_in[4];
    const float* b2 = (const float*)d_in[5];
    float* out = (float*)d_out;

    const int N = in_sizes[0] / 128;
    const int E = in_sizes[1] / 2;
    const int* src = ei;
    const int* dst = ei + E;
    const int nbuck = (N + BSIZE - 1) >> BSHIFT;        // 196 for N=100000
    const int nseg  = nbuck * 4;                        // 784 128-node segments
    const size_t capE = (size_t)nbuck << CAPSH;         // padded edge capacity

    float* dinv     = (float*)d_ws;                     // N
    int*   bcur     = (int*)(dinv + N);                 // 256
    int*   segbeg   = bcur + 256;                       // 1024
    int*   segcnt   = segbeg + 1024;                    // 1024
    short* w1t      = (short*)(segcnt + 1024);          // 128*128
    short* w2t      = w1t + 128 * 128;                  // 64*128
    unsigned* csr4  = (unsigned*)(w2t + 64 * 128);      // capE (12.8 MB)
    short* bufH     = (short*)(csr4 + capE);            // N*128 bf16 (h1')
    short* bufH2    = bufH + (size_t)N * 128;           // N*64  bf16 (h2')
    unsigned* aggb  = (unsigned*)(bufH2 + (size_t)N * 64); // N*64 bf16x2 (agg1)
    unsigned* ebuf  = (unsigned*)bufH2;                 // capE uints; aliases
                                                        // bufH2+aggb (ebuf dead
                                                        // before their writes)

    const int ntile = (E + 4095) / 4096;

    // ---- weight prep + bucket cursor init ----
    k_prep<<<97, 256, 0, stream>>>(W1, W2, w1t, w2t, bcur, nbuck);

    // ---- bucketed, phase-sorted CSR build (per-node atomics all in LDS) ----
    k_bucket<<<ntile, 256, 0, stream>>>(src, dst, bcur, ebuf, E, nbuck);
    k_bcsr<<<nbuck, BSIZE, 0, stream>>>(ebuf, bcur, dinv, csr4, segbeg, segcnt, N);

    // ---- layer 1 ----
    k_gemm1<<<(N + 63) / 64, 256, 0, stream>>>(x, w1t, dinv, bufH, N);
    k_pullacc128<<<nseg, 256, 0, stream>>>((const unsigned short*)bufH, csr4,
                                           segbeg, segcnt, dinv, aggb, N);

    // ---- layer 2 ----
    k_gemm2<<<(N + 63) / 64, 256, 0, stream>>>(aggb, b1, w2t, dinv, bufH2, N);
    k_pullacc64<<<nseg, 256, 0, stream>>>((const unsigned short*)bufH2, csr4,
                                          segbeg, segcnt, dinv, b2, out, N);
}

// Round 13
// 291.861 us; speedup vs baseline: 7.5302x; 7.5302x over previous
//
#include <hip/hip_runtime.h>
#include <hip/hip_bf16.h>

// GCN 2-layer forward, fp32 I/O. dinv folded into stored rows:
//   h1' = dinv * (x @ W1),  agg1 = dinv * (h1'[i] + sum_nbr h1'[s])
//   h2' = dinv * (relu(agg1+b1) @ W2),  out = dinv * (h2'[i] + sum h2'[s]) + b2
// so pull kernels are pure gather+add (no per-edge norm, no dinv reads).
// Packed 4B edge records; fixed-capacity bucketed CSR build with all
// per-node atomics in LDS; bf16 h/agg storage; MFMA bf16 GEMMs.
// r12 lesson: gather throughput = resident waves x outstanding loads —
// do NOT trade TLP for locality. This is r11's structure + 8K bucket tile.

typedef short short8v __attribute__((ext_vector_type(8)));   // 8 bf16 (4 VGPRs)
typedef float f32x4   __attribute__((ext_vector_type(4)));   // MFMA acc

#define BSHIFT 9           // bucket = dst >> 9 (span 512 nodes)
#define BSIZE  512
#define CAPSH  14          // per-bucket capacity 16384 (mean 8163, >40 sigma)
#define CAP    (1 << CAPSH)
#define TILE   8192        // edges per k_bucket block (dst-only LDS staging)

// RNE fp32 -> bf16 (finite inputs)
__device__ __forceinline__ short f2bf(float f) {
    unsigned u = __float_as_uint(f);
    return (short)((u + 0x7fffu + ((u >> 16) & 1u)) >> 16);
}
__device__ __forceinline__ unsigned pack2bf(float a, float b) {
    return (unsigned)(unsigned short)f2bf(a) | ((unsigned)(unsigned short)f2bf(b) << 16);
}
__device__ __forceinline__ float bflo(unsigned u) { return __uint_as_float(u << 16); }
__device__ __forceinline__ float bfhi(unsigned u) { return __uint_as_float(u & 0xffff0000u); }

// ---- W prep + bucket-cursor init (one launch) ----
__global__ void k_prep(const float* __restrict__ W1, const float* __restrict__ W2,
                       short* __restrict__ w1t, short* __restrict__ w2t,
                       int* __restrict__ bcur, int nbuck) {
    int b = blockIdx.x;
    int t = threadIdx.x;
    if (b == gridDim.x - 1) {                 // last block: init bucket cursors
        if (t < nbuck) bcur[t] = t << CAPSH;
        return;
    }
    int i = b * 256 + t;                      // 96 blocks cover 24576 elems
    if (i < 128 * 128) {
        int n = i >> 7, k = i & 127;
        w1t[i] = f2bf(W1[k * 128 + n]);
    } else {
        int j = i - 128 * 128;
        int n = j >> 7, k = j & 127;
        w2t[j] = f2bf(W2[k * 64 + n]);
    }
}

// ---- partition edges into packed ebuf: entry = (src<<9) | (dst&511).
// 8K-edge tile, dst staged in LDS (32 KB), src re-read coalesced in pass 3;
// bigger tile -> ~167 B per-bucket chunks -> less random-write line waste.
__global__ __launch_bounds__(256) void k_bucket(const int* __restrict__ src,
                                                const int* __restrict__ dst,
                                                int* __restrict__ bcur,
                                                unsigned* __restrict__ ebuf,
                                                int E, int nbuck) {
    __shared__ int sdst[TILE];     // 32 KB
    __shared__ int hist[256];
    __shared__ int base[256];
    int t = threadIdx.x;
    int e0 = blockIdx.x * TILE;
    for (int i = t; i < nbuck; i += 256) hist[i] = 0;
    __syncthreads();
    for (int i = 0; i < TILE / 256; ++i) {          // stage dst + LDS hist
        int k = i * 256 + t;
        int e = e0 + k;
        int d = (e < E) ? dst[e] : -1;
        sdst[k] = d;
        if (d >= 0) atomicAdd(&hist[d >> BSHIFT], 1);
    }
    __syncthreads();
    for (int b = t; b < nbuck; b += 256) {          // reserve chunks
        int c = hist[b];
        base[b] = c ? atomicAdd(&bcur[b], c) : 0;
        hist[b] = 0;
    }
    __syncthreads();
    for (int i = 0; i < TILE / 256; ++i) {          // grouped writes
        int k = i * 256 + t;
        int e = e0 + k;
        int d = sdst[k];
        if (d >= 0) {
            int s = src[e];                         // coalesced re-read (L2-cheap)
            int bk = d >> BSHIFT;
            int off = atomicAdd(&hist[bk], 1);
            ebuf[base[bk] + off] = ((unsigned)s << BSHIFT) | (unsigned)(d & (BSIZE - 1));
        }
    }
}

// ---- per-bucket merged: LDS stage -> hist -> scan -> deg/dinv/row_ptr
//      -> LDS-cursor scatter -> csr4 = src ----
__global__ __launch_bounds__(BSIZE) void k_bcsr(const unsigned* __restrict__ ebuf,
                                                const int* __restrict__ bcur,
                                                int* __restrict__ deg,
                                                int* __restrict__ row_ptr,
                                                float* __restrict__ dinv,
                                                unsigned* __restrict__ csr4, int n) {
    __shared__ unsigned edges[CAP];    // 64 KB
    __shared__ int hist[BSIZE];
    __shared__ int s[BSIZE];
    __shared__ int cur[BSIZE];
    int b = blockIdx.x;
    int t = threadIdx.x;
    hist[t] = 0;
    __syncthreads();
    int base = b << CAPSH;
    int cnt  = bcur[b] - base;
    int lo = b << BSHIFT;
    for (int k = t; k < cnt; k += BSIZE) {          // stage + LDS hist
        unsigned e = ebuf[base + k];
        edges[k] = e;
        atomicAdd(&hist[e & (BSIZE - 1)], 1);
    }
    __syncthreads();
    int v = hist[t];
    s[t] = v;
    __syncthreads();
    for (int off = 1; off < BSIZE; off <<= 1) {     // inclusive scan
        int add = (t >= off) ? s[t - off] : 0;
        __syncthreads();
        s[t] += add;
        __syncthreads();
    }
    int rp = base + s[t] - v;                       // padded-CSR offset
    cur[t] = rp;
    int node = lo + t;
    if (node < n) {
        deg[node]     = v;
        row_ptr[node] = rp;
        dinv[node]    = rsqrtf((float)(v + 1));
    }
    __syncthreads();
    for (int k = t; k < cnt; k += BSIZE) {          // scatter src -> csr4
        unsigned e = edges[k];
        int pos = atomicAdd(&cur[e & (BSIZE - 1)], 1);
        csr4[pos] = e >> BSHIFT;
    }
}

// ---- MFMA GEMM1: h1'[64rows,128] = dinv*(bf16(x) @ bf16(W1)) ----
#define LDP 136
__global__ __launch_bounds__(256) void k_gemm1(const float* __restrict__ x,
                                               const short* __restrict__ w1t,
                                               const float* __restrict__ dinv,
                                               short* __restrict__ h, int nrows) {
    __shared__ short xs[64 * LDP];
    __shared__ short wt[128 * LDP];
    int t = threadIdx.x;
    int row0 = blockIdx.x * 64;
    for (int i = 0; i < 16; ++i) {
        int idx = t + i * 256;
        int r = idx >> 5, c4 = idx & 31;
        float4 v = make_float4(0.f, 0.f, 0.f, 0.f);
        if (row0 + r < nrows) v = ((const float4*)x)[(size_t)(row0 + r) * 32 + c4];
        short4 o = make_short4(f2bf(v.x), f2bf(v.y), f2bf(v.z), f2bf(v.w));
        *(short4*)&xs[r * LDP + c4 * 4] = o;
    }
    for (int i = 0; i < 16; ++i) {
        int idx = t + i * 256;
        int n = idx >> 5, c4 = idx & 31;
        *(short4*)&wt[n * LDP + c4 * 4] = ((const short4*)w1t)[idx];
    }
    __syncthreads();
    int wave = t >> 6, lane = t & 63;
    int quad = lane >> 4, c = lane & 15;
    int m0 = wave * 16;
    f32x4 acc[8] = {};
    #pragma unroll
    for (int kc = 0; kc < 4; ++kc) {
        short8v a = *(const short8v*)&xs[(m0 + c) * LDP + kc * 32 + quad * 8];
        #pragma unroll
        for (int nt = 0; nt < 8; ++nt) {
            short8v b = *(const short8v*)&wt[(nt * 16 + c) * LDP + kc * 32 + quad * 8];
            acc[nt] = __builtin_amdgcn_mfma_f32_16x16x32_bf16(a, b, acc[nt], 0, 0, 0);
        }
    }
    #pragma unroll
    for (int r = 0; r < 4; ++r) {
        int row = row0 + m0 + quad * 4 + r;
        if (row < nrows) {
            float dr = dinv[row];                   // fold norm into stored row
            #pragma unroll
            for (int nt = 0; nt < 8; ++nt)
                h[(size_t)row * 128 + nt * 16 + c] = f2bf(acc[nt][r] * dr);
        }
    }
}

// ---- MFMA GEMM2: h2'[64rows,64] = dinv*(bf16(relu(aggb+b1)) @ bf16(W2)) ----
__global__ __launch_bounds__(256) void k_gemm2(const unsigned* __restrict__ aggb, // bf16x2
                                               const float* __restrict__ b1,
                                               const short* __restrict__ w2t,
                                               const float* __restrict__ dinv,
                                               short* __restrict__ h2, int nrows) {
    __shared__ short xs[64 * LDP];
    __shared__ short wt[64 * LDP];
    int t = threadIdx.x;
    int row0 = blockIdx.x * 64;
    for (int i = 0; i < 16; ++i) {                    // 64 rows x 64 bf16-pairs
        int idx = t + i * 256;
        int r = idx >> 6, cp = idx & 63;
        unsigned o = 0;
        if (row0 + r < nrows) {
            unsigned u = aggb[(size_t)(row0 + r) * 64 + cp];
            float2 bb = ((const float2*)b1)[cp];
            float vx = fmaxf(bflo(u) + bb.x, 0.f);
            float vy = fmaxf(bfhi(u) + bb.y, 0.f);
            o = pack2bf(vx, vy);
        }
        *(unsigned*)&xs[r * LDP + cp * 2] = o;
    }
    for (int i = 0; i < 8; ++i) {
        int idx = t + i * 256;
        int n = idx >> 5, c4 = idx & 31;
        *(short4*)&wt[n * LDP + c4 * 4] = ((const short4*)w2t)[idx];
    }
    __syncthreads();
    int wave = t >> 6, lane = t & 63;
    int quad = lane >> 4, c = lane & 15;
    int m0 = wave * 16;
    f32x4 acc[4] = {};
    #pragma unroll
    for (int kc = 0; kc < 4; ++kc) {
        short8v av = *(const short8v*)&xs[(m0 + c) * LDP + kc * 32 + quad * 8];
        #pragma unroll
        for (int nt = 0; nt < 4; ++nt) {
            short8v b = *(const short8v*)&wt[(nt * 16 + c) * LDP + kc * 32 + quad * 8];
            acc[nt] = __builtin_amdgcn_mfma_f32_16x16x32_bf16(av, b, acc[nt], 0, 0, 0);
        }
    }
    #pragma unroll
    for (int r = 0; r < 4; ++r) {
        int row = row0 + m0 + quad * 4 + r;
        if (row < nrows) {
            float dr = dinv[row];
            #pragma unroll
            for (int nt = 0; nt < 4; ++nt)
                h2[(size_t)row * 64 + nt * 16 + c] = f2bf(acc[nt][r] * dr);
        }
    }
}

// pull 128 feats: aggb[i] = bf16( dinv[i] * (h'[i] + sum_nbr h'[s]) ).
// One wave/node; pure gather+add inner loop (csr reads on scalar path).
__global__ __launch_bounds__(256) void k_pull128(const unsigned short* __restrict__ h,
                                                 const int* __restrict__ row_ptr,
                                                 const int* __restrict__ deg,
                                                 const unsigned* __restrict__ csr4,
                                                 const float* __restrict__ dinv,
                                                 unsigned* __restrict__ aggb, int n) {
    int wave = (blockIdx.x * 256 + threadIdx.x) >> 6;
    int lane = threadIdx.x & 63;
    if (wave >= n) return;
    int i = __builtin_amdgcn_readfirstlane(wave);
    float2 acc;
    {
        unsigned u = ((const unsigned*)(h + (size_t)i * 128))[lane];   // self
        acc.x = bflo(u);
        acc.y = bfhi(u);
    }
    int beg = row_ptr[i];
    int cnt = deg[i];
    int k = 0;
    for (; k + 8 <= cnt; k += 8) {
        unsigned sid[8];
        unsigned g[8];
        #pragma unroll
        for (int j = 0; j < 8; ++j) sid[j] = csr4[beg + k + j];
        #pragma unroll
        for (int j = 0; j < 8; ++j)
            g[j] = ((const unsigned*)(h + (size_t)sid[j] * 128))[lane];
        #pragma unroll
        for (int j = 0; j < 8; ++j) {
            acc.x += bflo(g[j]);
            acc.y += bfhi(g[j]);
        }
    }
    for (; k < cnt; ++k) {
        unsigned sid = csr4[beg + k];
        unsigned g = ((const unsigned*)(h + (size_t)sid * 128))[lane];
        acc.x += bflo(g);
        acc.y += bfhi(g);
    }
    float di = dinv[i];
    aggb[(size_t)i * 64 + lane] = pack2bf(acc.x * di, acc.y * di);
}

// pull 64 feats: out[i] = dinv[i]*(h'[i] + sum h'[s]) + b2. One wave/node.
__global__ __launch_bounds__(256) void k_pull64(const unsigned short* __restrict__ h,
                                                const int* __restrict__ row_ptr,
                                                const int* __restrict__ deg,
                                                const unsigned* __restrict__ csr4,
                                                const float* __restrict__ dinv,
                                                const float* __restrict__ b2,
                                                float* __restrict__ out, int n) {
    int wave = (blockIdx.x * 256 + threadIdx.x) >> 6;
    int lane = threadIdx.x & 63;
    if (wave >= n) return;
    int i = __builtin_amdgcn_readfirstlane(wave);
    float acc = __uint_as_float((unsigned)h[(size_t)i * 64 + lane] << 16);  // self
    int beg = row_ptr[i];
    int cnt = deg[i];
    int k = 0;
    for (; k + 8 <= cnt; k += 8) {
        unsigned sid[8];
        unsigned short u[8];
        #pragma unroll
        for (int j = 0; j < 8; ++j) sid[j] = csr4[beg + k + j];
        #pragma unroll
        for (int j = 0; j < 8; ++j) u[j] = h[(size_t)sid[j] * 64 + lane];
        #pragma unroll
        for (int j = 0; j < 8; ++j)
            acc += __uint_as_float((unsigned)u[j] << 16);
    }
    for (; k < cnt; ++k) {
        unsigned sid = csr4[beg + k];
        acc += __uint_as_float((unsigned)h[(size_t)sid * 64 + lane] << 16);
    }
    out[(size_t)i * 64 + lane] = acc * dinv[i] + b2[lane];
}

extern "C" void kernel_launch(void* const* d_in, const int* in_sizes, int n_in,
                              void* d_out, int out_size, void* d_ws, size_t ws_size,
                              hipStream_t stream) {
    const float* x  = (const float*)d_in[0];
    const int*   ei = (const int*)d_in[1];
    const float* W1 = (const float*)d_in[2];
    const float* b1 = (const float*)d_in[3];
    const float* W2 = (const float*)d_in[4];
    const float* b2 = (const float*)d_in[5];
    float* out = (float*)d_out;

    const int N = in_sizes[0] / 128;
    const int E = in_sizes[1] / 2;
    const int* src = ei;
    const int* dst = ei + E;
    const int nbuck = (N + BSIZE - 1) >> BSHIFT;        // 196 for N=100000
    const size_t capE = (size_t)nbuck << CAPSH;         // padded edge capacity

    float* dinv     = (float*)d_ws;                     // N
    int*   deg      = (int*)(dinv + N);                 // N
    int*   row_ptr  = deg + N;                          // N
    int*   bcur     = row_ptr + N;                      // 256
    short* w1t      = (short*)(bcur + 256);             // 128*128
    short* w2t      = w1t + 128 * 128;                  // 64*128
    unsigned* csr4  = (unsigned*)(w2t + 64 * 128);      // capE (12.8 MB)
    short* bufH     = (short*)(csr4 + capE);            // N*128 bf16 (h1')
    short* bufH2    = bufH + (size_t)N * 128;           // N*64  bf16 (h2')
    unsigned* aggb  = (unsigned*)(bufH2 + (size_t)N * 64); // N*64 bf16x2 (agg1)
    unsigned* ebuf  = (unsigned*)bufH2;                 // capE uints; aliases
                                                        // bufH2+aggb (ebuf dead
                                                        // before their writes)

    const int ntile = (E + TILE - 1) / TILE;            // 196 bucket tiles

    // ---- weight prep + bucket cursor init ----
    k_prep<<<97, 256, 0, stream>>>(W1, W2, w1t, w2t, bcur, nbuck);

    // ---- bucketed CSR build (per-node atomics all in LDS) ----
    k_bucket<<<ntile, 256, 0, stream>>>(src, dst, bcur, ebuf, E, nbuck);
    k_bcsr<<<nbuck, BSIZE, 0, stream>>>(ebuf, bcur, deg, row_ptr, dinv, csr4, N);

    // ---- layer 1 ----
    k_gemm1<<<(N + 63) / 64, 256, 0, stream>>>(x, w1t, dinv, bufH, N);
    k_pull128<<<(N + 3) / 4, 256, 0, stream>>>((const unsigned short*)bufH, row_ptr, deg, csr4, dinv, aggb, N);

    // ---- layer 2 ----
    k_gemm2<<<(N + 63) / 64, 256, 0, stream>>>(aggb, b1, w2t, dinv, bufH2, N);
    k_pull64<<<(N + 3) / 4, 256, 0, stream>>>((const unsigned short*)bufH2, row_ptr, deg, csr4, dinv, b2, out, N);
}